// Round 5
// baseline (206.321 us; speedup 1.0000x reference)
//
#include <hip/hip_runtime.h>
#include <hip/hip_bf16.h>

#define B_N 256
#define L_Q 64
#define FEAT_N 2048
#define UNITS_N 512
#define EMB_N 256
#define VOCAB_N 32000

typedef __attribute__((ext_vector_type(8))) short bf16x8;
typedef __attribute__((ext_vector_type(4))) float f32x4;

__device__ __forceinline__ unsigned short f2bf(float x) {
  union { float f; unsigned int u; } c; c.f = x;
  unsigned int u = c.u + 0x7FFFu + ((c.u >> 16) & 1u);
  return (unsigned short)(u >> 16);
}

__device__ __forceinline__ float sigmoidf_(float x) { return 1.0f / (1.0f + __expf(-x)); }

// A-fragment layout for mfma_f32_16x16x32_bf16 (KS = K/32):
//   ushort index = ((rt*KS + ks)*64 + (lq*16+lr))*8 + j ; row = rt*16+lr, k = ks*32+lq*8+j
__device__ __forceinline__ void store_frag4(unsigned short* base, int KS, int row, int k0,
                                            float a, float b, float c, float d) {
  int rt = row >> 4, lr = row & 15;
  int ks = k0 >> 5, lq = (k0 >> 3) & 3, j0 = k0 & 7;
  union { unsigned long long u; unsigned short s[4]; } p;
  p.s[0] = f2bf(a); p.s[1] = f2bf(b); p.s[2] = f2bf(c); p.s[3] = f2bf(d);
  *reinterpret_cast<unsigned long long*>(base + (((rt * KS + ks) * 64) + (lq * 16 + lr)) * 8 + j0) = p.u;
}

__device__ __forceinline__ void gload_lds16(const void* g, void* lds) {
  __builtin_amdgcn_global_load_lds(
      (const __attribute__((address_space(1))) unsigned int*)(uintptr_t)g,
      (__attribute__((address_space(3))) unsigned int*)(unsigned)(uintptr_t)lds,
      16, 0, 0);
}

// B-fragment weight layout: idx = (((nt*4+ct)*KS + ks)*64 + l)*8 + j
__device__ __forceinline__ void wfrag_one(const float* __restrict__ W, int N, int KS,
                                          unsigned short* __restrict__ dst, int tid, int gruMap) {
  int l = tid & 63;
  int ks = (tid >> 6) % KS;
  int cts = tid / (64 * KS);
  int ct = cts & 3, nt = cts >> 2;
  int nb = gruMap ? (nt < 8 ? nt * 64 : 1024 + (nt - 8) * 64) : nt * 64;
  int ncol = nb + ct * 16 + (l & 15);
  int k0 = ks * 32 + (l >> 4) * 8;
  union { bf16x8 v; unsigned short s[8]; } fr;
#pragma unroll
  for (int j = 0; j < 8; ++j) fr.s[j] = f2bf(W[(size_t)(k0 + j) * N + ncol]);
  *reinterpret_cast<bf16x8*>(dst + (size_t)tid * 8) = fr.v;
}

// ---- fused prep: W1 frags, hidden/emb frags, and small-weight frag conversions
__global__ void k_prep_all(const float* __restrict__ W1, unsigned short* __restrict__ W1s,
                           const float* __restrict__ hidden,
                           const float* __restrict__ emb_table,
                           const int* __restrict__ tok,
                           unsigned short* __restrict__ hfrag,
                           unsigned short* __restrict__ xinfrag,
                           const float* __restrict__ W2, unsigned short* __restrict__ W2f,
                           const float* __restrict__ W3, unsigned short* __restrict__ W3f,
                           const float* __restrict__ gruK, unsigned short* __restrict__ gruf,
                           const float* __restrict__ fc1W, unsigned short* __restrict__ fc1f) {
  int bb = blockIdx.x;
  if (bb < 512) {
    int t = bb * 256 + threadIdx.x;            // W1: one 16B frag each
    int l = t & 63;
    int c = (t >> 6) & 31;
    int kt = t >> 11;
    int n = c * 16 + (l & 15);
    int k0 = kt * 32 + (l >> 4) * 8;
    union { bf16x8 v; unsigned short s[8]; } fr;
#pragma unroll
    for (int j = 0; j < 8; ++j) fr.s[j] = f2bf(W1[(size_t)(k0 + j) * UNITS_N + n]);
    *reinterpret_cast<bf16x8*>(W1s + (size_t)t * 8) = fr.v;
  } else if (bb < 704) {
    int t = (bb - 512) * 256 + threadIdx.x;
    if (t < 32768) {
      int b = t >> 7, k0 = (t & 127) * 4;
      const float* s = hidden + (size_t)b * UNITS_N + k0;
      store_frag4(hfrag, 16, b, k0, s[0], s[1], s[2], s[3]);
    } else if (t < 49152) {
      int t2 = t - 32768;
      int b = t2 >> 6, e0 = (t2 & 63) * 4;
      const float* s = emb_table + (size_t)tok[b] * EMB_N + e0;
      store_frag4(xinfrag, 24, b, 512 + e0, s[0], s[1], s[2], s[3]);
    }
  } else if (bb < 832) {
    wfrag_one(W2, 512, 16, W2f, (bb - 704) * 256 + threadIdx.x, 0);
  } else if (bb < 1472) {
    wfrag_one(W3, 512, 80, W3f, (bb - 832) * 256 + threadIdx.x, 0);
  } else if (bb < 1856) {
    wfrag_one(gruK, 1536, 24, gruf, (bb - 1472) * 256 + threadIdx.x, 1);
  } else {
    wfrag_one(fc1W, 512, 16, fc1f, (bb - 1856) * 256 + threadIdx.x, 0);
  }
}

// ---- split-K small GEMM (unchanged)
template <int MODE>
__launch_bounds__(256)
__global__ void k_small2(const unsigned short* __restrict__ Afrag, int KS,
                         const unsigned short* __restrict__ Bfrag,
                         const float* __restrict__ bias,
                         float* __restrict__ outF, int N,
                         unsigned short* __restrict__ outFrag, int KSo) {
  constexpr int NCT = (MODE == 2) ? 8 : 4;
  __shared__ f32x4 red[4][2][NCT][64];
  int t = threadIdx.x, w = t >> 6, l = t & 63;
  int nt = blockIdx.x;
  int mb = blockIdx.y;
  int KSq = KS >> 2;

  f32x4 acc[2][NCT];
#pragma unroll
  for (int rt = 0; rt < 2; ++rt)
#pragma unroll
    for (int ct = 0; ct < NCT; ++ct) acc[rt][ct] = (f32x4){0.f, 0.f, 0.f, 0.f};

  for (int s = 0; s < KSq; ++s) {
    int ks = w * KSq + s;
    bf16x8 af[2];
#pragma unroll
    for (int rt = 0; rt < 2; ++rt)
      af[rt] = *reinterpret_cast<const bf16x8*>(Afrag + (((size_t)(mb * 2 + rt) * KS + ks) * 64 + l) * 8);
#pragma unroll
    for (int ct = 0; ct < NCT; ++ct) {
      int tile = (MODE == 2) ? (ct < 4 ? nt : 8 + nt) : nt;
      int cts = ct & 3;
      bf16x8 bf = *reinterpret_cast<const bf16x8*>(Bfrag + (((size_t)(tile * 4 + cts) * KS + ks) * 64 + l) * 8);
#pragma unroll
      for (int rt = 0; rt < 2; ++rt)
        acc[rt][ct] = __builtin_amdgcn_mfma_f32_16x16x32_bf16(af[rt], bf, acc[rt][ct], 0, 0, 0);
    }
  }

#pragma unroll
  for (int rt = 0; rt < 2; ++rt)
#pragma unroll
    for (int ct = 0; ct < NCT; ++ct) red[w][rt][ct][l] = acc[rt][ct];
  __syncthreads();

#pragma unroll
  for (int si = 0; si < 2; ++si) {
    int s = t + si * 256;
    int l2 = s & 63, ct = (s >> 6) & 3, rt = s >> 8;
    f32x4 v = red[0][rt][ct][l2];
#pragma unroll
    for (int ww = 1; ww < 4; ++ww) v += red[ww][rt][ct][l2];
    int col = nt * 64 + ct * 16 + (l2 & 15);
    int row0 = mb * 32 + rt * 16 + (l2 >> 4) * 4;
    if (MODE == 2) {
      f32x4 vh = red[0][rt][ct + 4][l2];
#pragma unroll
      for (int ww = 1; ww < 4; ++ww) vh += red[ww][rt][ct + 4][l2];
      float bz = bias[col], bh = bias[1024 + col];
#pragma unroll
      for (int i = 0; i < 4; ++i) {
        float hv = (1.f - sigmoidf_(v[i] + bz)) * tanhf(vh[i] + bh);
        int row = row0 + i;
        outF[(size_t)row * UNITS_N + col] = hv;
        int k = col;
        outFrag[(((size_t)(row >> 4) * KSo + (k >> 5)) * 64 + (((k >> 3) & 3) * 16 + (row & 15))) * 8 + (k & 7)] = f2bf(hv);
      }
    } else {
      float bv = bias[col];
#pragma unroll
      for (int i = 0; i < 4; ++i) {
        float vv = v[i] + bv;
        int row = row0 + i;
        if (MODE == 0) {
          outF[(size_t)row * N + col] = vv;
        } else {
          int k = col;
          outFrag[(((size_t)(row >> 4) * KSo + (k >> 5)) * 64 + (((k >> 3) & 3) * 16 + (row & 15))) * 8 + (k & 7)] = f2bf(vv);
        }
      }
    }
  }
}

// ---- GEMM1 fused: one block per batch, 8 waves (wr in {0,1}: 32 rows, wc in {0..3}: 64 cols
// per half). B staged via LDS double-half pipeline: per K32-tile, cols split into two 16KB
// halves; stage of next half issued BEFORE compute of current half (stage-early, T14), so
// the barrier drain finds loads complete. A in-register from features (issued before stages
// so A-waits don't drain them). Epilogue: tanh*V partial -> LDS reduce -> in-block softmax
// -> attn out -> fused context + tanh-concat frags.
__launch_bounds__(512, 2)
__global__ void k_gemm1f(const float* __restrict__ features,
                         const unsigned short* __restrict__ W1s,
                         const float* __restrict__ hproj,
                         const float* __restrict__ b1,
                         const float* __restrict__ V,
                         const float* __restrict__ hidden,
                         float* __restrict__ attn_out,
                         unsigned short* __restrict__ tcfrag) {
  __shared__ unsigned short Bb[2][16 * 64 * 8];   // 2 x 16 KB halves
  __shared__ float wlog[8][32];
  __shared__ float aL[64];

  int b = blockIdx.x;
  int t = threadIdx.x, w = t >> 6, l = t & 63;
  int wr = w >> 2, wc = w & 3;

  f32x4 acc[2][8];
#pragma unroll
  for (int rt = 0; rt < 2; ++rt)
#pragma unroll
    for (int ct = 0; ct < 8; ++ct) acc[rt][ct] = (f32x4){0.f, 0.f, 0.f, 0.f};

  const float* Arow = features + ((size_t)(b * 64 + wr * 32 + (l & 15))) * FEAT_N + ((l >> 4) * 8);
  const char* W1c = (const char*)W1s;

  // prologue: stage half0 of kt=0
#pragma unroll
  for (int i = 0; i < 2; ++i)
    gload_lds16(W1c + ((size_t)(0 * 32 + 0 + w * 2 + i) << 10) + (size_t)l * 16,
                (char*)Bb[0] + ((w * 2 + i) << 10));
  __syncthreads();

  for (int kt = 0; kt < 64; ++kt) {
    // ---- P0: A loads (first!), stage half1(kt), compute half0(kt)
    float4 x0a = *reinterpret_cast<const float4*>(Arow + kt * 32);
    float4 x1a = *reinterpret_cast<const float4*>(Arow + kt * 32 + 4);
    float4 x0b = *reinterpret_cast<const float4*>(Arow + (size_t)16 * FEAT_N + kt * 32);
    float4 x1b = *reinterpret_cast<const float4*>(Arow + (size_t)16 * FEAT_N + kt * 32 + 4);
#pragma unroll
    for (int i = 0; i < 2; ++i)
      gload_lds16(W1c + ((size_t)(kt * 32 + 16 + w * 2 + i) << 10) + (size_t)l * 16,
                  (char*)Bb[1] + ((w * 2 + i) << 10));
    bf16x8 af[2];
    {
      union { bf16x8 v; unsigned short s[8]; } u;
      u.s[0] = f2bf(x0a.x); u.s[1] = f2bf(x0a.y); u.s[2] = f2bf(x0a.z); u.s[3] = f2bf(x0a.w);
      u.s[4] = f2bf(x1a.x); u.s[5] = f2bf(x1a.y); u.s[6] = f2bf(x1a.z); u.s[7] = f2bf(x1a.w);
      af[0] = u.v;
      u.s[0] = f2bf(x0b.x); u.s[1] = f2bf(x0b.y); u.s[2] = f2bf(x0b.z); u.s[3] = f2bf(x0b.w);
      u.s[4] = f2bf(x1b.x); u.s[5] = f2bf(x1b.y); u.s[6] = f2bf(x1b.z); u.s[7] = f2bf(x1b.w);
      af[1] = u.v;
    }
#pragma unroll
    for (int ct = 0; ct < 4; ++ct) {
      bf16x8 bfr = *reinterpret_cast<const bf16x8*>(&Bb[0][((wc * 4 + ct) * 64 + l) * 8]);
      acc[0][ct] = __builtin_amdgcn_mfma_f32_16x16x32_bf16(af[0], bfr, acc[0][ct], 0, 0, 0);
      acc[1][ct] = __builtin_amdgcn_mfma_f32_16x16x32_bf16(af[1], bfr, acc[1][ct], 0, 0, 0);
    }
    __syncthreads();
    // ---- P1: stage half0(kt+1), compute half1(kt)
    if (kt + 1 < 64) {
#pragma unroll
      for (int i = 0; i < 2; ++i)
        gload_lds16(W1c + ((size_t)((kt + 1) * 32 + w * 2 + i) << 10) + (size_t)l * 16,
                    (char*)Bb[0] + ((w * 2 + i) << 10));
    }
#pragma unroll
    for (int ct = 0; ct < 4; ++ct) {
      bf16x8 bfr = *reinterpret_cast<const bf16x8*>(&Bb[1][((wc * 4 + ct) * 64 + l) * 8]);
      acc[0][4 + ct] = __builtin_amdgcn_mfma_f32_16x16x32_bf16(af[0], bfr, acc[0][4 + ct], 0, 0, 0);
      acc[1][4 + ct] = __builtin_amdgcn_mfma_f32_16x16x32_bf16(af[1], bfr, acc[1][4 + ct], 0, 0, 0);
    }
    __syncthreads();
  }

  // partial logits over this wave's 128 cols (4 in half0, 4 in half1)
  float rowpart[8];
#pragma unroll
  for (int i = 0; i < 8; ++i) rowpart[i] = 0.f;
#pragma unroll
  for (int ct = 0; ct < 8; ++ct) {
    int col = (ct < 4 ? wc * 64 + ct * 16 : 256 + wc * 64 + (ct - 4) * 16) + (l & 15);
    float hb = hproj[(size_t)b * UNITS_N + col] + b1[col];
    float vv = V[col];
#pragma unroll
    for (int rt = 0; rt < 2; ++rt)
#pragma unroll
      for (int i = 0; i < 4; ++i)
        rowpart[rt * 4 + i] += tanhf(acc[rt][ct][i] + hb) * vv;
  }
#pragma unroll
  for (int m = 1; m <= 8; m <<= 1)
#pragma unroll
    for (int i = 0; i < 8; ++i) rowpart[i] += __shfl_xor(rowpart[i], m, 64);
  if ((l & 15) == 0) {
    int g = l >> 4;
#pragma unroll
    for (int rt = 0; rt < 2; ++rt)
#pragma unroll
      for (int i = 0; i < 4; ++i)
        wlog[w][rt * 16 + g * 4 + i] = rowpart[rt * 4 + i];
  }
  __syncthreads();
  if (t < 64) {
    int wr2 = t >> 5, rl = t & 31;
    float x = wlog[wr2 * 4 + 0][rl] + wlog[wr2 * 4 + 1][rl] +
              wlog[wr2 * 4 + 2][rl] + wlog[wr2 * 4 + 3][rl];
    float mx = x;
#pragma unroll
    for (int m = 1; m < 64; m <<= 1) mx = fmaxf(mx, __shfl_xor(mx, m, 64));
    float e = __expf(x - mx);
    float s = e;
#pragma unroll
    for (int m = 1; m < 64; m <<= 1) s += __shfl_xor(s, m, 64);
    float a = e / s;
    aL[t] = a;
    attn_out[(size_t)b * 64 + t] = a;
  }
  __syncthreads();

  // fused context: 512 threads x 4 cols
  {
    const float* F = features + (size_t)b * 64 * FEAT_N + t * 4;
    float a0 = 0.f, a1 = 0.f, a2 = 0.f, a3 = 0.f;
#pragma unroll 4
    for (int lr = 0; lr < 64; ++lr) {
      float4 f = *reinterpret_cast<const float4*>(F + (size_t)lr * FEAT_N);
      float av = aL[lr];
      a0 += av * f.x; a1 += av * f.y; a2 += av * f.z; a3 += av * f.w;
    }
    store_frag4(tcfrag, 80, b, t * 4, tanhf(a0), tanhf(a1), tanhf(a2), tanhf(a3));
  }
  if (t < 128) {
    const float* H = hidden + (size_t)b * UNITS_N + t * 4;
    store_frag4(tcfrag, 80, b, 2048 + t * 4, tanhf(H[0]), tanhf(H[1]), tanhf(H[2]), tanhf(H[3]));
  }
}

// ---- fc2: out = x1 @ fc2_W + fc2_b. grid (500, 2): 128 rows x 64 cols per block.
__launch_bounds__(256)
__global__ void k_fc2(const unsigned short* __restrict__ x1frag,
                      const float* __restrict__ W, const float* __restrict__ bias,
                      float* __restrict__ out) {
  __shared__ unsigned short Bb[4 * 64 * 8];
  int t = threadIdx.x, w = t >> 6, l = t & 63;
  int n0 = blockIdx.x * 64;
  int mh = blockIdx.y;
  f32x4 acc[2][4];
#pragma unroll
  for (int r = 0; r < 2; ++r)
#pragma unroll
    for (int c = 0; c < 4; ++c) acc[r][c] = (f32x4){0.f, 0.f, 0.f, 0.f};

  int sn = t & 63, kc = t >> 6;
  unsigned short* wdst = &Bb[(((sn >> 4) * 64) + ((sn & 15) | (kc << 4))) * 8];
  const float* Wp = W + n0 + sn;
  float wreg[8];
#pragma unroll
  for (int j = 0; j < 8; ++j) wreg[j] = Wp[(size_t)(kc * 8 + j) * VOCAB_N];

  for (int kt = 0; kt < 16; ++kt) {
    __syncthreads();
    {
      union { bf16x8 v; unsigned short s[8]; } p;
#pragma unroll
      for (int j = 0; j < 8; ++j) p.s[j] = f2bf(wreg[j]);
      *reinterpret_cast<bf16x8*>(wdst) = p.v;
    }
    __syncthreads();
    if (kt < 15) {
#pragma unroll
      for (int j = 0; j < 8; ++j) wreg[j] = Wp[(size_t)((kt + 1) * 32 + kc * 8 + j) * VOCAB_N];
    }
    bf16x8 bf[4];
#pragma unroll
    for (int c = 0; c < 4; ++c) bf[c] = *reinterpret_cast<const bf16x8*>(&Bb[((c * 64) + l) * 8]);
#pragma unroll
    for (int rti = 0; rti < 2; ++rti) {
      int rtg = mh * 8 + w * 2 + rti;
      bf16x8 af = *reinterpret_cast<const bf16x8*>(x1frag + ((size_t)(rtg * 16 + kt) * 64 + l) * 8);
#pragma unroll
      for (int c = 0; c < 4; ++c)
        acc[rti][c] = __builtin_amdgcn_mfma_f32_16x16x32_bf16(af, bf[c], acc[rti][c], 0, 0, 0);
    }
  }
#pragma unroll
  for (int c = 0; c < 4; ++c) {
    int col = n0 + c * 16 + (l & 15);
    float bv = bias[col];
#pragma unroll
    for (int rti = 0; rti < 2; ++rti)
#pragma unroll
      for (int i = 0; i < 4; ++i) {
        int row = mh * 128 + w * 32 + rti * 16 + (l >> 4) * 4 + i;
        out[(size_t)row * VOCAB_N + col] = acc[rti][c][i] + bv;
      }
  }
}

extern "C" void kernel_launch(void* const* d_in, const int* in_sizes, int n_in,
                              void* d_out, int out_size, void* d_ws, size_t ws_size,
                              hipStream_t stream) {
  const int*   tok        = (const int*)d_in[0];
  const float* features   = (const float*)d_in[1];
  const float* hidden     = (const float*)d_in[2];
  const float* W1         = (const float*)d_in[3];
  const float* b1         = (const float*)d_in[4];
  const float* W2         = (const float*)d_in[5];
  const float* b2         = (const float*)d_in[6];
  const float* V          = (const float*)d_in[7];
  // d_in[8] = bV: cancels in softmax
  const float* W3         = (const float*)d_in[9];
  const float* b3         = (const float*)d_in[10];
  const float* emb_table  = (const float*)d_in[11];
  const float* gru_kernel = (const float*)d_in[12];
  // d_in[13] = gru_rec: unused (h0 == 0); r-gate columns of gru_kernel also dead
  const float* gru_bias   = (const float*)d_in[14];
  const float* fc1_W      = (const float*)d_in[15];
  const float* fc1_b      = (const float*)d_in[16];
  const float* fc2_W      = (const float*)d_in[17];
  const float* fc2_b      = (const float*)d_in[18];

  float* out_logits = (float*)d_out;
  float* out_h      = out_logits + (size_t)B_N * VOCAB_N;
  float* out_attn   = out_h + (size_t)B_N * UNITS_N;

  char* ws = (char*)d_ws;
  unsigned short* W1s     = (unsigned short*)(ws);               // 2,097,152
  float*          hproj   = (float*)(ws + 2097152);              //   524,288
  unsigned short* hfrag   = (unsigned short*)(ws + 2621440);     //   262,144
  unsigned short* tcfrag  = (unsigned short*)(ws + 2883584);     // 1,310,720
  unsigned short* xinfrag = (unsigned short*)(ws + 4194304);     //   393,216
  unsigned short* hnfrag  = (unsigned short*)(ws + 4587520);     //   262,144
  unsigned short* x1frag  = (unsigned short*)(ws + 4849664);     //   262,144
  unsigned short* W2f     = (unsigned short*)(ws + 5242880);     //   524,288
  unsigned short* W3f     = (unsigned short*)(ws + 5767168);     // 2,621,440
  unsigned short* gruf    = (unsigned short*)(ws + 8388608);     // 1,572,864
  unsigned short* fc1f    = (unsigned short*)(ws + 9961472);     //   524,288

  k_prep_all<<<dim3(1984), dim3(256), 0, stream>>>(W1, W1s, hidden, emb_table, tok,
                                                   hfrag, xinfrag, W2, W2f, W3, W3f,
                                                   gru_kernel, gruf, fc1_W, fc1f);
  // hproj = hidden @ W2 + b2
  k_small2<0><<<dim3(8, 8), dim3(256), 0, stream>>>(hfrag, 16, W2f, b2, hproj, 512,
                                                    (unsigned short*)nullptr, 0);
  // fused GEMM1 + softmax + attn + context + tanh-concat frags
  k_gemm1f<<<dim3(256), dim3(512), 0, stream>>>(features, W1s, hproj, b1, V, hidden,
                                                out_attn, tcfrag);
  // cvh = tc @ W3 + b3 -> xin frags (k 0..511)
  k_small2<1><<<dim3(8, 8), dim3(256), 0, stream>>>(tcfrag, 80, W3f, b3, (float*)nullptr, 0,
                                                    xinfrag, 24);
  // gru: z/hh GEMM fused with activation -> out_h + hn frags
  k_small2<2><<<dim3(8, 8), dim3(256), 0, stream>>>(xinfrag, 24, gruf, gru_bias, out_h, 512,
                                                    hnfrag, 16);
  // x1 = h_new @ fc1_W + fc1_b -> frags
  k_small2<1><<<dim3(8, 8), dim3(256), 0, stream>>>(hnfrag, 16, fc1f, fc1_b, (float*)nullptr, 0,
                                                    x1frag, 16);
  // logits_out = x1 @ fc2_W + fc2_b
  k_fc2<<<dim3(500, 2), dim3(256), 0, stream>>>(x1frag, fc2_W, fc2_b, out_logits);
}

// Round 7
// 141.033 us; speedup vs baseline: 1.4629x; 1.4629x over previous
//
#include <hip/hip_runtime.h>
#include <hip/hip_bf16.h>

#define B_N 256
#define L_Q 64
#define FEAT_N 2048
#define UNITS_N 512
#define EMB_N 256
#define VOCAB_N 32000

typedef __attribute__((ext_vector_type(8))) short bf16x8;
typedef __attribute__((ext_vector_type(4))) float f32x4;

__device__ __forceinline__ unsigned short f2bf(float x) {
  union { float f; unsigned int u; } c; c.f = x;
  unsigned int u = c.u + 0x7FFFu + ((c.u >> 16) & 1u);
  return (unsigned short)(u >> 16);
}

__device__ __forceinline__ float sigmoidf_(float x) { return 1.0f / (1.0f + __expf(-x)); }

// A-fragment layout for mfma_f32_16x16x32_bf16 (KS = K/32):
//   ushort index = ((rt*KS + ks)*64 + (lq*16+lr))*8 + j ; row = rt*16+lr, k = ks*32+lq*8+j
__device__ __forceinline__ void store_frag4(unsigned short* base, int KS, int row, int k0,
                                            float a, float b, float c, float d) {
  int rt = row >> 4, lr = row & 15;
  int ks = k0 >> 5, lq = (k0 >> 3) & 3, j0 = k0 & 7;
  union { unsigned long long u; unsigned short s[4]; } p;
  p.s[0] = f2bf(a); p.s[1] = f2bf(b); p.s[2] = f2bf(c); p.s[3] = f2bf(d);
  *reinterpret_cast<unsigned long long*>(base + (((rt * KS + ks) * 64) + (lq * 16 + lr)) * 8 + j0) = p.u;
}

__device__ __forceinline__ void gload_lds16(const void* g, void* lds) {
  __builtin_amdgcn_global_load_lds(
      (const __attribute__((address_space(1))) unsigned int*)(uintptr_t)g,
      (__attribute__((address_space(3))) unsigned int*)(unsigned)(uintptr_t)lds,
      16, 0, 0);
}

// B-fragment weight layout: idx = (((nt*4+ct)*KS + ks)*64 + l)*8 + j
__device__ __forceinline__ void wfrag_one(const float* __restrict__ W, int N, int KS,
                                          unsigned short* __restrict__ dst, int tid, int gruMap) {
  int l = tid & 63;
  int ks = (tid >> 6) % KS;
  int cts = tid / (64 * KS);
  int ct = cts & 3, nt = cts >> 2;
  int nb = gruMap ? (nt < 8 ? nt * 64 : 1024 + (nt - 8) * 64) : nt * 64;
  int ncol = nb + ct * 16 + (l & 15);
  int k0 = ks * 32 + (l >> 4) * 8;
  union { bf16x8 v; unsigned short s[8]; } fr;
#pragma unroll
  for (int j = 0; j < 8; ++j) fr.s[j] = f2bf(W[(size_t)(k0 + j) * N + ncol]);
  *reinterpret_cast<bf16x8*>(dst + (size_t)tid * 8) = fr.v;
}

// ---- fused prep
__global__ void k_prep_all(const float* __restrict__ W1, unsigned short* __restrict__ W1s,
                           const float* __restrict__ hidden,
                           const float* __restrict__ emb_table,
                           const int* __restrict__ tok,
                           unsigned short* __restrict__ hfrag,
                           unsigned short* __restrict__ xinfrag,
                           const float* __restrict__ W2, unsigned short* __restrict__ W2f,
                           const float* __restrict__ W3, unsigned short* __restrict__ W3f,
                           const float* __restrict__ gruK, unsigned short* __restrict__ gruf,
                           const float* __restrict__ fc1W, unsigned short* __restrict__ fc1f) {
  int bb = blockIdx.x;
  if (bb < 512) {
    int t = bb * 256 + threadIdx.x;
    int l = t & 63;
    int c = (t >> 6) & 31;
    int kt = t >> 11;
    int n = c * 16 + (l & 15);
    int k0 = kt * 32 + (l >> 4) * 8;
    union { bf16x8 v; unsigned short s[8]; } fr;
#pragma unroll
    for (int j = 0; j < 8; ++j) fr.s[j] = f2bf(W1[(size_t)(k0 + j) * UNITS_N + n]);
    *reinterpret_cast<bf16x8*>(W1s + (size_t)t * 8) = fr.v;
  } else if (bb < 704) {
    int t = (bb - 512) * 256 + threadIdx.x;
    if (t < 32768) {
      int b = t >> 7, k0 = (t & 127) * 4;
      const float* s = hidden + (size_t)b * UNITS_N + k0;
      store_frag4(hfrag, 16, b, k0, s[0], s[1], s[2], s[3]);
    } else if (t < 49152) {
      int t2 = t - 32768;
      int b = t2 >> 6, e0 = (t2 & 63) * 4;
      const float* s = emb_table + (size_t)tok[b] * EMB_N + e0;
      store_frag4(xinfrag, 24, b, 512 + e0, s[0], s[1], s[2], s[3]);
    }
  } else if (bb < 832) {
    wfrag_one(W2, 512, 16, W2f, (bb - 704) * 256 + threadIdx.x, 0);
  } else if (bb < 1472) {
    wfrag_one(W3, 512, 80, W3f, (bb - 832) * 256 + threadIdx.x, 0);
  } else if (bb < 1856) {
    wfrag_one(gruK, 1536, 24, gruf, (bb - 1472) * 256 + threadIdx.x, 1);
  } else {
    wfrag_one(fc1W, 512, 16, fc1f, (bb - 1856) * 256 + threadIdx.x, 0);
  }
}

// ---- split-K small GEMM (unchanged, proven)
template <int MODE>
__launch_bounds__(256)
__global__ void k_small2(const unsigned short* __restrict__ Afrag, int KS,
                         const unsigned short* __restrict__ Bfrag,
                         const float* __restrict__ bias,
                         float* __restrict__ outF, int N,
                         unsigned short* __restrict__ outFrag, int KSo) {
  constexpr int NCT = (MODE == 2) ? 8 : 4;
  __shared__ f32x4 red[4][2][NCT][64];
  int t = threadIdx.x, w = t >> 6, l = t & 63;
  int nt = blockIdx.x;
  int mb = blockIdx.y;
  int KSq = KS >> 2;

  f32x4 acc[2][NCT];
#pragma unroll
  for (int rt = 0; rt < 2; ++rt)
#pragma unroll
    for (int ct = 0; ct < NCT; ++ct) acc[rt][ct] = (f32x4){0.f, 0.f, 0.f, 0.f};

  for (int s = 0; s < KSq; ++s) {
    int ks = w * KSq + s;
    bf16x8 af[2];
#pragma unroll
    for (int rt = 0; rt < 2; ++rt)
      af[rt] = *reinterpret_cast<const bf16x8*>(Afrag + (((size_t)(mb * 2 + rt) * KS + ks) * 64 + l) * 8);
#pragma unroll
    for (int ct = 0; ct < NCT; ++ct) {
      int tile = (MODE == 2) ? (ct < 4 ? nt : 8 + nt) : nt;
      int cts = ct & 3;
      bf16x8 bf = *reinterpret_cast<const bf16x8*>(Bfrag + (((size_t)(tile * 4 + cts) * KS + ks) * 64 + l) * 8);
#pragma unroll
      for (int rt = 0; rt < 2; ++rt)
        acc[rt][ct] = __builtin_amdgcn_mfma_f32_16x16x32_bf16(af[rt], bf, acc[rt][ct], 0, 0, 0);
    }
  }

#pragma unroll
  for (int rt = 0; rt < 2; ++rt)
#pragma unroll
    for (int ct = 0; ct < NCT; ++ct) red[w][rt][ct][l] = acc[rt][ct];
  __syncthreads();

#pragma unroll
  for (int si = 0; si < 2; ++si) {
    int s = t + si * 256;
    int l2 = s & 63, ct = (s >> 6) & 3, rt = s >> 8;
    f32x4 v = red[0][rt][ct][l2];
#pragma unroll
    for (int ww = 1; ww < 4; ++ww) v += red[ww][rt][ct][l2];
    int col = nt * 64 + ct * 16 + (l2 & 15);
    int row0 = mb * 32 + rt * 16 + (l2 >> 4) * 4;
    if (MODE == 2) {
      f32x4 vh = red[0][rt][ct + 4][l2];
#pragma unroll
      for (int ww = 1; ww < 4; ++ww) vh += red[ww][rt][ct + 4][l2];
      float bz = bias[col], bh = bias[1024 + col];
#pragma unroll
      for (int i = 0; i < 4; ++i) {
        float hv = (1.f - sigmoidf_(v[i] + bz)) * tanhf(vh[i] + bh);
        int row = row0 + i;
        outF[(size_t)row * UNITS_N + col] = hv;
        int k = col;
        outFrag[(((size_t)(row >> 4) * KSo + (k >> 5)) * 64 + (((k >> 3) & 3) * 16 + (row & 15))) * 8 + (k & 7)] = f2bf(hv);
      }
    } else {
      float bv = bias[col];
#pragma unroll
      for (int i = 0; i < 4; ++i) {
        float vv = v[i] + bv;
        int row = row0 + i;
        if (MODE == 0) {
          outF[(size_t)row * N + col] = vv;
        } else {
          int k = col;
          outFrag[(((size_t)(row >> 4) * KSo + (k >> 5)) * 64 + (((k >> 3) & 3) * 16 + (row & 15))) * 8 + (k & 7)] = f2bf(vv);
        }
      }
    }
  }
}

// ==== GEMM1: plain-HIP 2-phase pipeline ====
// BM=64, BN=256 (h halves), BK=32, grid 512 (2 blocks/CU), 4 waves.
// Per step kt: issue A-load(kt+2) regs; issue async STAGE B(kt+1)->Bb[(kt+1)&1];
// convert A(kt+1) regs -> Ab[(kt+1)&1]; MFMA from Ab[kt&1]/Bb[kt&1]; ONE __syncthreads.
// The B-stage gets the whole convert+MFMA phase before the barrier drain; A regs are
// loaded 2 steps ahead of consumption so the convert never stalls on HBM.

#define G7_LOADA(S0, S1, KF)                                       \
  { const float* p_ = Ap + (size_t)(KF) * 32;                      \
    S0 = *reinterpret_cast<const float4*>(p_);                     \
    S1 = *reinterpret_cast<const float4*>(p_ + 4); }

#define G7_STAGEB(KF, BUF)                                                          \
  { _Pragma("unroll")                                                               \
    for (int i_ = 0; i_ < 4; ++i_) {                                                \
      int s_ = w * 4 + i_;                                                          \
      gload_lds16(W1c + ((size_t)((KF) * 32 + h * 16 + s_) << 10) + (size_t)l * 16, \
                  BbC + (size_t)(BUF) * 16384 + (s_ << 10));                        \
    } }

#define G7_CONVA(S0, S1, BUF)                                      \
  { union { bf16x8 v; unsigned short s8[8]; } u_;                  \
    u_.s8[0] = f2bf(S0.x); u_.s8[1] = f2bf(S0.y);                  \
    u_.s8[2] = f2bf(S0.z); u_.s8[3] = f2bf(S0.w);                  \
    u_.s8[4] = f2bf(S1.x); u_.s8[5] = f2bf(S1.y);                  \
    u_.s8[6] = f2bf(S1.z); u_.s8[7] = f2bf(S1.w);                  \
    *reinterpret_cast<bf16x8*>(&Ab[BUF][awi]) = u_.v; }

#define G7_BODY(KT, L0, L1, C0, C1)                                           \
  { const int kt_ = (KT);                                                     \
    if (kt_ + 2 < 64) G7_LOADA(L0, L1, kt_ + 2);                              \
    if (kt_ + 1 < 64) {                                                       \
      G7_STAGEB(kt_ + 1, (kt_ + 1) & 1);                                      \
      G7_CONVA(C0, C1, (kt_ + 1) & 1);                                        \
    }                                                                         \
    bf16x8 af_[4];                                                            \
    _Pragma("unroll")                                                         \
    for (int rt_ = 0; rt_ < 4; ++rt_)                                         \
      af_[rt_] = *reinterpret_cast<const bf16x8*>(                            \
          &Ab[kt_ & 1][((rt_ * 4 + (l >> 4)) * 16 + (l & 15)) * 8]);          \
    _Pragma("unroll")                                                         \
    for (int ct_ = 0; ct_ < 4; ++ct_) {                                       \
      bf16x8 bfr_ = *reinterpret_cast<const bf16x8*>(                         \
          &Bb[kt_ & 1][((w * 4 + ct_) * 64 + l) * 8]);                        \
      _Pragma("unroll")                                                       \
      for (int rt_ = 0; rt_ < 4; ++rt_)                                       \
        acc[rt_][ct_] = __builtin_amdgcn_mfma_f32_16x16x32_bf16(              \
            af_[rt_], bfr_, acc[rt_][ct_], 0, 0, 0);                          \
    }                                                                         \
    __syncthreads();                                                          \
  }

__launch_bounds__(256, 2)
__global__ void k_gemm1p(const float* __restrict__ features,
                         const unsigned short* __restrict__ W1s,
                         const float* __restrict__ hproj,
                         const float* __restrict__ b1,
                         const float* __restrict__ V,
                         float* __restrict__ partials) {
  __shared__ unsigned short Bb[2][8192];   // 2 x 16 KB
  __shared__ unsigned short Ab[2][2048];   // 2 x 4 KB
  __shared__ float wlog[4][64];

  int t = threadIdx.x, w = t >> 6, l = t & 63;
  int bid = blockIdx.x;
  int swz = (bid & 7) * 64 + (bid >> 3);   // bijective; h=0/1 of same mb on one XCD
  int h = swz & 1;
  int mb = swz >> 1;

  f32x4 acc[4][4];
#pragma unroll
  for (int rt = 0; rt < 4; ++rt)
#pragma unroll
    for (int ct = 0; ct < 4; ++ct) acc[rt][ct] = (f32x4){0.f, 0.f, 0.f, 0.f};

  int r = t >> 2, q = t & 3;
  const float* Ap = features + (size_t)(mb * 64 + r) * FEAT_N + q * 8;
  const int awi = (((r >> 4) * 4 + q) * 16 + (r & 15)) * 8;
  const char* W1c = (const char*)W1s;
  char* BbC = (char*)Bb;

  float4 a00, a01, a10, a11;

  // prologue: A(0)->set0, A(1)->set1, B(0)->Bb[0]; convert A(0)->Ab[0]
  G7_LOADA(a00, a01, 0);
  G7_LOADA(a10, a11, 1);
  G7_STAGEB(0, 0);
  G7_CONVA(a00, a01, 0);
  __syncthreads();

  for (int kt2 = 0; kt2 < 64; kt2 += 2) {
    G7_BODY(kt2,     a00, a01, a10, a11);   // load A(kt2+2)->set0; convert A(kt2+1)=set1
    G7_BODY(kt2 + 1, a10, a11, a00, a01);   // load A(kt2+3)->set1; convert A(kt2+2)=set0
  }

  // epilogue: partial logits over this half's 256 cols
  float rowpart[16];
#pragma unroll
  for (int i = 0; i < 16; ++i) rowpart[i] = 0.f;
#pragma unroll
  for (int ct = 0; ct < 4; ++ct) {
    int col = h * 256 + w * 64 + ct * 16 + (l & 15);
    float hb = hproj[(size_t)mb * UNITS_N + col] + b1[col];
    float vv = V[col];
#pragma unroll
    for (int rt = 0; rt < 4; ++rt)
#pragma unroll
      for (int i = 0; i < 4; ++i)
        rowpart[rt * 4 + i] += tanhf(acc[rt][ct][i] + hb) * vv;
  }
#pragma unroll
  for (int m = 1; m <= 8; m <<= 1)
#pragma unroll
    for (int i = 0; i < 16; ++i) rowpart[i] += __shfl_xor(rowpart[i], m, 64);
  if ((l & 15) == 0) {
    int g = l >> 4;
#pragma unroll
    for (int rt = 0; rt < 4; ++rt)
#pragma unroll
      for (int i = 0; i < 4; ++i)
        wlog[w][rt * 16 + g * 4 + i] = rowpart[rt * 4 + i];
  }
  __syncthreads();
  if (t < 64) {
    float x = wlog[0][t] + wlog[1][t] + wlog[2][t] + wlog[3][t];
    partials[h * 16384 + mb * 64 + t] = x;
  }
}

// ---- softmax + context + tanh-concat frags; 2 batches per block (16 waves/CU)
__global__ void k_context(const float* __restrict__ features,
                          const float* __restrict__ partials,
                          const float* __restrict__ hidden,
                          unsigned short* __restrict__ tcfrag,
                          float* __restrict__ attn_out) {
  __shared__ float aL[2][64];
  int t = threadIdx.x;           // 0..1023
  int half = t >> 9, tt = t & 511;
  int b = blockIdx.x * 2 + half;
  if (tt < 64) {
    float x = partials[b * 64 + tt] + partials[16384 + b * 64 + tt];
    float mx = x;
#pragma unroll
    for (int m = 1; m < 64; m <<= 1) mx = fmaxf(mx, __shfl_xor(mx, m, 64));
    float e = __expf(x - mx);
    float s = e;
#pragma unroll
    for (int m = 1; m < 64; m <<= 1) s += __shfl_xor(s, m, 64);
    float a = e / s;
    aL[half][tt] = a;
    attn_out[(size_t)b * 64 + tt] = a;
  }
  __syncthreads();
  const float* F = features + (size_t)b * 64 * FEAT_N + tt * 4;
  float a0 = 0.f, a1 = 0.f, a2 = 0.f, a3 = 0.f;
#pragma unroll 4
  for (int lr = 0; lr < 64; ++lr) {
    float4 f = *reinterpret_cast<const float4*>(F + (size_t)lr * FEAT_N);
    float av = aL[half][lr];
    a0 += av * f.x; a1 += av * f.y; a2 += av * f.z; a3 += av * f.w;
  }
  store_frag4(tcfrag, 80, b, tt * 4, tanhf(a0), tanhf(a1), tanhf(a2), tanhf(a3));
  if (tt < 128) {
    const float* H = hidden + (size_t)b * UNITS_N + tt * 4;
    store_frag4(tcfrag, 80, b, 2048 + tt * 4, tanhf(H[0]), tanhf(H[1]), tanhf(H[2]), tanhf(H[3]));
  }
}

// ---- fc2: grid (500, 2)
__launch_bounds__(256)
__global__ void k_fc2(const unsigned short* __restrict__ x1frag,
                      const float* __restrict__ W, const float* __restrict__ bias,
                      float* __restrict__ out) {
  __shared__ unsigned short Bb[4 * 64 * 8];
  int t = threadIdx.x, w = t >> 6, l = t & 63;
  int n0 = blockIdx.x * 64;
  int mh = blockIdx.y;
  f32x4 acc[2][4];
#pragma unroll
  for (int r = 0; r < 2; ++r)
#pragma unroll
    for (int c = 0; c < 4; ++c) acc[r][c] = (f32x4){0.f, 0.f, 0.f, 0.f};

  int sn = t & 63, kc = t >> 6;
  unsigned short* wdst = &Bb[(((sn >> 4) * 64) + ((sn & 15) | (kc << 4))) * 8];
  const float* Wp = W + n0 + sn;
  float wreg[8];
#pragma unroll
  for (int j = 0; j < 8; ++j) wreg[j] = Wp[(size_t)(kc * 8 + j) * VOCAB_N];

  for (int kt = 0; kt < 16; ++kt) {
    __syncthreads();
    {
      union { bf16x8 v; unsigned short s[8]; } p;
#pragma unroll
      for (int j = 0; j < 8; ++j) p.s[j] = f2bf(wreg[j]);
      *reinterpret_cast<bf16x8*>(wdst) = p.v;
    }
    __syncthreads();
    if (kt < 15) {
#pragma unroll
      for (int j = 0; j < 8; ++j) wreg[j] = Wp[(size_t)((kt + 1) * 32 + kc * 8 + j) * VOCAB_N];
    }
    bf16x8 bf[4];
#pragma unroll
    for (int c = 0; c < 4; ++c) bf[c] = *reinterpret_cast<const bf16x8*>(&Bb[((c * 64) + l) * 8]);
#pragma unroll
    for (int rti = 0; rti < 2; ++rti) {
      int rtg = mh * 8 + w * 2 + rti;
      bf16x8 af = *reinterpret_cast<const bf16x8*>(x1frag + ((size_t)(rtg * 16 + kt) * 64 + l) * 8);
#pragma unroll
      for (int c = 0; c < 4; ++c)
        acc[rti][c] = __builtin_amdgcn_mfma_f32_16x16x32_bf16(af, bf[c], acc[rti][c], 0, 0, 0);
    }
  }
#pragma unroll
  for (int c = 0; c < 4; ++c) {
    int col = n0 + c * 16 + (l & 15);
    float bv = bias[col];
#pragma unroll
    for (int rti = 0; rti < 2; ++rti)
#pragma unroll
      for (int i = 0; i < 4; ++i) {
        int row = mh * 128 + w * 32 + rti * 16 + (l >> 4) * 4 + i;
        out[(size_t)row * VOCAB_N + col] = acc[rti][c][i] + bv;
      }
  }
}

extern "C" void kernel_launch(void* const* d_in, const int* in_sizes, int n_in,
                              void* d_out, int out_size, void* d_ws, size_t ws_size,
                              hipStream_t stream) {
  const int*   tok        = (const int*)d_in[0];
  const float* features   = (const float*)d_in[1];
  const float* hidden     = (const float*)d_in[2];
  const float* W1         = (const float*)d_in[3];
  const float* b1         = (const float*)d_in[4];
  const float* W2         = (const float*)d_in[5];
  const float* b2         = (const float*)d_in[6];
  const float* V          = (const float*)d_in[7];
  // d_in[8] = bV: cancels in softmax
  const float* W3         = (const float*)d_in[9];
  const float* b3         = (const float*)d_in[10];
  const float* emb_table  = (const float*)d_in[11];
  const float* gru_kernel = (const float*)d_in[12];
  // d_in[13] = gru_rec: unused (h0 == 0); r-gate columns of gru_kernel also dead
  const float* gru_bias   = (const float*)d_in[14];
  const float* fc1_W      = (const float*)d_in[15];
  const float* fc1_b      = (const float*)d_in[16];
  const float* fc2_W      = (const float*)d_in[17];
  const float* fc2_b      = (const float*)d_in[18];

  float* out_logits = (float*)d_out;
  float* out_h      = out_logits + (size_t)B_N * VOCAB_N;
  float* out_attn   = out_h + (size_t)B_N * UNITS_N;

  char* ws = (char*)d_ws;
  unsigned short* W1s     = (unsigned short*)(ws);               // 2,097,152
  float*          hproj   = (float*)(ws + 2097152);              //   524,288
  unsigned short* hfrag   = (unsigned short*)(ws + 2621440);     //   262,144
  unsigned short* tcfrag  = (unsigned short*)(ws + 2883584);     // 1,310,720
  unsigned short* xinfrag = (unsigned short*)(ws + 4194304);     //   393,216
  unsigned short* hnfrag  = (unsigned short*)(ws + 4587520);     //   262,144
  unsigned short* x1frag  = (unsigned short*)(ws + 4849664);     //   262,144
  float*          partials= (float*)(ws + 5111808);              //   131,072
  unsigned short* W2f     = (unsigned short*)(ws + 5242880);     //   524,288
  unsigned short* W3f     = (unsigned short*)(ws + 5767168);     // 2,621,440
  unsigned short* gruf    = (unsigned short*)(ws + 8388608);     // 1,572,864
  unsigned short* fc1f    = (unsigned short*)(ws + 9961472);     //   524,288

  k_prep_all<<<dim3(1984), dim3(256), 0, stream>>>(W1, W1s, hidden, emb_table, tok,
                                                   hfrag, xinfrag, W2, W2f, W3, W3f,
                                                   gru_kernel, gruf, fc1_W, fc1f);
  // hproj = hidden @ W2 + b2
  k_small2<0><<<dim3(8, 8), dim3(256), 0, stream>>>(hfrag, 16, W2f, b2, hproj, 512,
                                                    (unsigned short*)nullptr, 0);
  // partial logits (2-phase pipelined)
  k_gemm1p<<<dim3(512), dim3(256), 0, stream>>>(features, W1s, hproj, b1, V, partials);
  // softmax + context + tanh-concat frags
  k_context<<<dim3(128), dim3(1024), 0, stream>>>(features, partials, hidden, tcfrag, out_attn);
  // cvh = tc @ W3 + b3 -> xin frags
  k_small2<1><<<dim3(8, 8), dim3(256), 0, stream>>>(tcfrag, 80, W3f, b3, (float*)nullptr, 0,
                                                    xinfrag, 24);
  // gru: z/hh GEMM fused with activation -> out_h + hn frags
  k_small2<2><<<dim3(8, 8), dim3(256), 0, stream>>>(xinfrag, 24, gruf, gru_bias, out_h, 512,
                                                    hnfrag, 16);
  // x1 = h_new @ fc1_W + fc1_b -> frags
  k_small2<1><<<dim3(8, 8), dim3(256), 0, stream>>>(hnfrag, 16, fc1f, fc1_b, (float*)nullptr, 0,
                                                    x1frag, 16);
  // logits_out = x1 @ fc2_W + fc2_b
  k_fc2<<<dim3(500, 2), dim3(256), 0, stream>>>(x1frag, fc2_W, fc2_b, out_logits);
}